// Round 12
// baseline (1953.634 us; speedup 1.0000x reference)
//
#include <hip/hip_runtime.h>

// CAGenerator: 64-step neural CA — 2 dispatches/step, fence-free.
// R12: gemm3 (upd = W3*H) folded INTO k1: each k1 block computes its
// 64-channel H chunk, round-trips it through LDS (C-layout -> B-octet,
// wave-local so no barrier), does 12 MFMA of W3[:,chunk] x Hchunk and
// atomicAdds the partial upd into Upd[80][NPIX]. H never hits global
// memory. k2 is now a pure VALU epilogue: alpha/live mask from Upd ch0,
// Snew = (Sold + Upd + b3)*live, Smf16 write, and zeroing of the OTHER
// Upd buffer (ping-pong -> no read-then-zero halo race).
// Folded: Wc = W2@W1 (512x720), bc = W2@b1+b2. mask=uniform()<1.0 -> no RNG.
// State kept twice: Sf32 channel-major + Smf16 pixel-major fp16.
// K-permutation kp = tap*80+ci: B-fragment = one ds_read_b128 from msT.

#define NPIX 8192
#define T_ALIVE 0.01f

typedef _Float16 f16;
typedef __attribute__((ext_vector_type(8)))  _Float16 h8_t;
typedef __attribute__((ext_vector_type(4)))  _Float16 h4_t;
typedef __attribute__((ext_vector_type(16))) float    fx16;

// ---------------------------------------------------------------------------
// Prep
// ---------------------------------------------------------------------------
__global__ __launch_bounds__(256) void tr512(
    const float* __restrict__ W2, float* __restrict__ W2T)
{
    __shared__ float t[32][33];
    const int bx = blockIdx.x & 15, by = blockIdx.x >> 4;
    const int x = threadIdx.x & 31, y8 = threadIdx.x >> 5;
#pragma unroll
    for (int r = 0; r < 32; r += 8)
        t[r + y8][x] = W2[(size_t)(by * 32 + r + y8) * 512 + bx * 32 + x];
    __syncthreads();
#pragma unroll
    for (int r = 0; r < 32; r += 8)
        W2T[(size_t)(bx * 32 + r + y8) * 512 + by * 32 + x] = t[x][r + y8];
}

__global__ __launch_bounds__(256) void wc32(
    const float* __restrict__ W2T, const float* __restrict__ W1,
    float* __restrict__ Wc)
{
    __shared__ float As[16][32];
    __shared__ float Bs[16][32];
    const int tid = threadIdx.x;
    const int ty = tid >> 3, tx = tid & 7;
    const int m0 = blockIdx.y * 32, n0 = blockIdx.x * 32;
    float acc[4] = {0.f, 0.f, 0.f, 0.f};

    for (int k0 = 0; k0 < 512; k0 += 16) {
#pragma unroll
        for (int t = 0; t < 2; ++t) {
            const int idx = tid + t * 256;
            const int r = idx >> 5, c = idx & 31;
            As[r][c] = W2T[(size_t)(k0 + r) * 512 + m0 + c];
            const int n = n0 + c;
            Bs[r][c] = (n < 720) ? W1[(size_t)(k0 + r) * 720 + n] : 0.f;
        }
        __syncthreads();
#pragma unroll
        for (int kk = 0; kk < 16; ++kk) {
            const float a = As[kk][ty];
#pragma unroll
            for (int j = 0; j < 4; ++j)
                acc[j] = fmaf(a, Bs[kk][tx * 4 + j], acc[j]);
        }
        __syncthreads();
    }
    const int m = m0 + ty;
#pragma unroll
    for (int j = 0; j < 4; ++j) {
        const int n = n0 + tx * 4 + j;
        if (n < 720) Wc[(size_t)m * 720 + n] = acc[j];
    }
}

__global__ __launch_bounds__(256) void bc_k(
    const float* __restrict__ W2, const float* __restrict__ b1,
    const float* __restrict__ b2, float* __restrict__ bc)
{
    const int m = blockIdx.x * 256 + threadIdx.x;
    if (m >= 512) return;
    float a = b2[m];
    for (int h = 0; h < 512; ++h) a += W2[m * 512 + h] * b1[h];
    bc[m] = a;
}

// 32x32x16 A-frags, K permuted (kp = tap*80+ci), 720 = 45*16 exactly.
__global__ __launch_bounds__(256) void swz_wc2(
    const float* __restrict__ Wc, f16* __restrict__ Wcsw2)
{
    const int idx = blockIdx.x * 256 + threadIdx.x;
    if (idx >= 45 * 16 * 64) return;
    const int lane = idx & 63;
    const int t = idx >> 6;
    const int mtg = t & 15, ks = t >> 4;
    const int m = mtg * 32 + (lane & 31);
    const int k0 = ks * 16 + (lane >> 5) * 8;
    h8_t v;
#pragma unroll
    for (int j = 0; j < 8; ++j) {
        const int kp = k0 + j;
        const int tap = kp / 80, ci = kp - tap * 80;
        v[j] = (f16)Wc[(size_t)m * 720 + ci * 9 + tap];
    }
    *(h8_t*)(Wcsw2 + (size_t)idx * 8) = v;
}

// 32x32x16 A-frags for W3 (80x512 padded to 96 rows).
__global__ __launch_bounds__(256) void swz_w32(
    const float* __restrict__ W3, f16* __restrict__ W3sw2)
{
    const int idx = blockIdx.x * 256 + threadIdx.x;
    if (idx >= 32 * 3 * 64) return;
    const int lane = idx & 63;
    const int t = idx >> 6;
    const int mt = t % 3, ks2 = t / 3;
    const int m = mt * 32 + (lane & 31);
    const int k0 = ks2 * 16 + (lane >> 5) * 8;
    h8_t v;
#pragma unroll
    for (int j = 0; j < 8; ++j)
        v[j] = (f16)((m < 80) ? W3[(size_t)m * 512 + k0 + j] : 0.f);
    *(h8_t*)(W3sw2 + (size_t)idx * 8) = v;
}

__global__ __launch_bounds__(256) void seed_k(
    const float* __restrict__ z, float* __restrict__ Sf32,
    f16* __restrict__ Smf16)
{
    const int idx = blockIdx.x * 256 + threadIdx.x;
    if (idx >= 640) return;
    const int b = idx / 80, c = idx - b * 80;
    const int n = b * 1024 + 16 * 32 + 16;
    const float v = (c == 0) ? 1.f : z[b * 100 + (c - 1)];
    Sf32[(size_t)c * NPIX + n] = v;
    Smf16[(size_t)n * 80 + c] = (f16)v;
}

// ---------------------------------------------------------------------------
// K1: H = relu(Wc * im2col(S)); then upd-partial = W3[:,chunk] * Hchunk via
// LDS round-trip + 12 MFMA, atomicAdd into Upd. grid (64, 8): x = 4-row band
// (img b = pb>>3, rows y0..y0+3), y = mb (64-channel chunk). Wave w = row.
// ---------------------------------------------------------------------------
__global__ __launch_bounds__(256) void k1_gemmH(
    const f16* __restrict__ Smf16, const f16* __restrict__ Wcsw2,
    const float* __restrict__ bc, const f16* __restrict__ W3sw2,
    float* __restrict__ Upd)
{
    __shared__ f16  msT[16320];     // 10 octets x (6 rows x 34 px) x 8 halfs
    __shared__ f16  Hsw[8192];      // 8 co x 4 row x 32 px x 8 halfs, 16 KB
    __shared__ float bcL[64];

    const int tid = threadIdx.x;
    const int lane = tid & 63, w = tid >> 6;
    const int li = lane & 31, q2 = lane >> 5;
    const int pb = blockIdx.x, mb = blockIdx.y;
    const int b = pb >> 3, y0 = (pb & 7) * 4;
    const int gb = b * 1024;

    if (tid < 64) bcL[tid] = bc[mb * 64 + tid];
    // stage masked state from pixel-major fp16 (contiguous 16B per (px,cc))
    for (int idx = tid; idx < 2040; idx += 256) {
        const int p = idx / 10, cc = idx - p * 10;
        const int r = p / 34, xi = p - r * 34;
        const int gx = xi - 1, y = y0 - 1 + r;
        h8_t v;
        if (((unsigned)y < 32u) & ((unsigned)gx < 32u)) {
            v = *(const h8_t*)(Smf16 + (size_t)(gb + y * 32 + gx) * 80 + cc * 8);
        } else {
#pragma unroll
            for (int j = 0; j < 8; ++j) v[j] = (f16)0.f;
        }
        *(h8_t*)(msT + (size_t)(cc * 204 + p) * 8) = v;
    }
    __syncthreads();

    int pxh[9];
#pragma unroll
    for (int t = 0; t < 9; ++t)
        pxh[t] = ((t / 3) * 34 + li + (t % 3)) * 8;
    const int wbase = w * 272;      // w * 34 * 8

    fx16 acc[2];
#pragma unroll
    for (int i = 0; i < 2; ++i)
#pragma unroll
        for (int r = 0; r < 16; ++r) acc[i][r] = 0.f;

    h8_t abuf[4][2];                // depth-4 prefetch ring
#pragma unroll
    for (int pk = 0; pk < 4; ++pk)
#pragma unroll
        for (int i = 0; i < 2; ++i)
            abuf[pk][i] = *(const h8_t*)(Wcsw2 +
                (((size_t)pk * 16 + (mb * 2 + i)) * 64 + lane) * 8);

#pragma unroll
    for (int ks = 0; ks < 45; ++ks) {
        const int o0 = 2 * ks, o1 = 2 * ks + 1;
        const int a0 = (o0 % 10) * 1632 + wbase + pxh[o0 / 10];
        const int a1 = (o1 % 10) * 1632 + wbase + pxh[o1 / 10];
        const h8_t bf = *(const h8_t*)(msT + (q2 ? a1 : a0));
        h8_t av[2];
#pragma unroll
        for (int i = 0; i < 2; ++i) av[i] = abuf[ks & 3][i];
        if (ks + 4 < 45) {
#pragma unroll
            for (int i = 0; i < 2; ++i)
                abuf[ks & 3][i] = *(const h8_t*)(Wcsw2 +
                    (((size_t)(ks + 4) * 16 + (mb * 2 + i)) * 64 + lane) * 8);
        }
#pragma unroll
        for (int i = 0; i < 2; ++i)
            acc[i] = __builtin_amdgcn_mfma_f32_32x32x16_f16(
                av[i], bf, acc[i], 0, 0, 0);
    }

    // epilogue A: relu(acc + bc) -> Hsw (LDS octet layout, own row only)
#pragma unroll
    for (int i = 0; i < 2; ++i) {
#pragma unroll
        for (int aa = 0; aa < 4; ++aa) {
            const int chl = i * 32 + 8 * aa + 4 * q2;
            const int co = i * 4 + aa;             // local channel octet
            h4_t v4;
#pragma unroll
            for (int rb = 0; rb < 4; ++rb)
                v4[rb] = (f16)fmaxf(acc[i][aa * 4 + rb] + bcL[chl + rb], 0.f);
            *(h4_t*)(Hsw + ((size_t)(co * 4 + w) * 32 + li) * 8 + 4 * q2) = v4;
        }
    }
    // epilogue B: upd-partial = W3[:, mb*64:+64] x Hchunk (wave-local read)
    fx16 acc3[3];
#pragma unroll
    for (int mt = 0; mt < 3; ++mt)
#pragma unroll
        for (int r = 0; r < 16; ++r) acc3[mt][r] = 0.f;
#pragma unroll
    for (int t = 0; t < 4; ++t) {
        const int ks2 = mb * 4 + t;
        const h8_t bf = *(const h8_t*)(Hsw +
            ((size_t)((t * 2 + q2) * 4 + w) * 32 + li) * 8);
#pragma unroll
        for (int mt = 0; mt < 3; ++mt) {
            const h8_t a = *(const h8_t*)(W3sw2 +
                (((size_t)ks2 * 3 + mt) * 64 + lane) * 8);
            acc3[mt] = __builtin_amdgcn_mfma_f32_32x32x16_f16(
                a, bf, acc3[mt], 0, 0, 0);
        }
    }
    // epilogue C: atomic accumulate into Upd
    const size_t px = (size_t)(gb + (y0 + w) * 32 + li);
#pragma unroll
    for (int mt = 0; mt < 3; ++mt)
#pragma unroll
        for (int aa = 0; aa < 4; ++aa)
#pragma unroll
            for (int rb = 0; rb < 4; ++rb) {
                const int ch = mt * 32 + rb + 8 * aa + 4 * q2;
                if (ch < 80)
                    atomicAdd(&Upd[(size_t)ch * NPIX + px],
                              acc3[mt][aa * 4 + rb]);
            }
}

// ---------------------------------------------------------------------------
// K2: pure VALU epilogue. grid 256: img b = blk>>5, row y = blk&31.
// alphaN = Sold_ch0 + Upd_ch0 + b3[0]; live mask; Snew = (Sold+Upd+b3)*lv;
// Smf16 write; zero UpdZ (next step's accumulator).
// ---------------------------------------------------------------------------
__global__ __launch_bounds__(256) void k2_update(
    const float* __restrict__ b3,
    const float* __restrict__ Sold, float* __restrict__ Snew,
    f16* __restrict__ Smf16,
    const float* __restrict__ UpdC, float* __restrict__ UpdZ)
{
    __shared__ float alphaO3[96];
    __shared__ float alphaN3[96];
    __shared__ float b3L[80];
    __shared__ float livef[32];

    const int tid = threadIdx.x;
    const int blk = blockIdx.x;
    const int b = blk >> 5, y = blk & 31;
    const int gb = b * 1024;
    const int base = gb + y * 32;

    if (tid < 80) b3L[tid] = b3[tid];
    if (tid < 96) {
        const int r = tid >> 5, x = tid & 31, yy = y - 1 + r;
        if ((unsigned)yy < 32u) {
            const float so = Sold[gb + yy * 32 + x];
            alphaO3[tid] = so;
            alphaN3[tid] = so + UpdC[gb + yy * 32 + x] + b3[0];
        } else {
            alphaO3[tid] = -1e30f;
            alphaN3[tid] = -1e30f;
        }
    }
    __syncthreads();

    if (tid < 32) {
        float mN = -1e30f, mO = -1e30f;
#pragma unroll
        for (int r = 0; r < 3; ++r)
#pragma unroll
            for (int dx = -1; dx <= 1; ++dx) {
                const int xx = tid + dx;
                if ((unsigned)xx < 32u) {
                    mN = fmaxf(mN, alphaN3[r * 32 + xx]);
                    mO = fmaxf(mO, alphaO3[r * 32 + xx]);
                }
            }
        livef[tid] = (mN > T_ALIVE && mO > T_ALIVE) ? 1.f : 0.f;
    }
    __syncthreads();

    // 80 ch x 32 px in channel-quads (640 quads of 4 ch at one px)
    for (int q = tid; q < 640; q += 256) {
        const int cq = q >> 5, x = q & 31;
        const float lv = livef[x];
        const size_t pxg = (size_t)(base + x);
        h4_t v4;
#pragma unroll
        for (int rb = 0; rb < 4; ++rb) {
            const int ch = cq * 4 + rb;
            const size_t idx = (size_t)ch * NPIX + pxg;
            const float v = (Sold[idx] + UpdC[idx] + b3L[ch]) * lv;
            Snew[idx] = v;
            v4[rb] = (f16)v;
        }
        *(h4_t*)(Smf16 + pxg * 80 + cq * 4) = v4;
    }
    // zero the next step's accumulator rows
    for (int q = tid; q < 2560; q += 256) {
        const int ch = q >> 5, x = q & 31;
        UpdZ[(size_t)ch * NPIX + base + x] = 0.f;
    }
}

// ---------------------------------------------------------------------------
extern "C" void kernel_launch(void* const* d_in, const int* in_sizes, int n_in,
                              void* d_out, int out_size, void* d_ws, size_t ws_size,
                              hipStream_t stream)
{
    const float* z  = (const float*)d_in[0];
    const float* W1 = (const float*)d_in[1];   // 512 x 720
    const float* b1 = (const float*)d_in[2];
    const float* W2 = (const float*)d_in[3];   // 512 x 512
    const float* b2 = (const float*)d_in[4];
    const float* W3 = (const float*)d_in[5];   // 80 x 512
    const float* b3 = (const float*)d_in[6];

    char* ws = (char*)d_ws;
    float* S0    = (float*)ws;  ws += (size_t)80 * NPIX * 4;
    float* S1    = (float*)ws;  ws += (size_t)80 * NPIX * 4;
    f16*   Sm0   = (f16*)ws;   ws += (size_t)NPIX * 80 * 2;
    f16*   Sm1   = (f16*)ws;   ws += (size_t)NPIX * 80 * 2;
    float* Upd0  = (float*)ws;  ws += (size_t)80 * NPIX * 4;
    float* Upd1  = (float*)ws;  ws += (size_t)80 * NPIX * 4;
    float* bc    = (float*)ws;  ws += 512 * 4;
    float* Wc    = (float*)ws;  ws += (size_t)512 * 720 * 4;
    float* W2T   = (float*)ws;  ws += (size_t)512 * 512 * 4;
    f16*   Wcsw2 = (f16*)ws;   ws += (size_t)45 * 16 * 64 * 8 * 2;
    f16*   W3sw2 = (f16*)ws;   ws += (size_t)32 * 3 * 64 * 8 * 2;

    hipMemsetAsync(S0, 0, (size_t)80 * NPIX * 4, stream);
    hipMemsetAsync(Sm0, 0, (size_t)NPIX * 80 * 2, stream);
    hipMemsetAsync(Upd0, 0, (size_t)80 * NPIX * 4, stream);
    hipMemsetAsync(Upd1, 0, (size_t)80 * NPIX * 4, stream);
    seed_k<<<3, 256, 0, stream>>>(z, S0, Sm0);
    tr512<<<256, 256, 0, stream>>>(W2, W2T);
    wc32<<<dim3(23, 16), 256, 0, stream>>>(W2T, W1, Wc);
    bc_k<<<2, 256, 0, stream>>>(W2, b1, b2, bc);
    swz_wc2<<<180, 256, 0, stream>>>(Wc, Wcsw2);
    swz_w32<<<24, 256, 0, stream>>>(W3, W3sw2);

    float* Scur = S0;  float* Snxt = S1;
    f16*   Mcur = Sm0; f16*   Mnxt = Sm1;
    for (int s = 0; s < 64; ++s) {
        float* UpdC = (s & 1) ? Upd1 : Upd0;   // k1 accumulates (pre-zeroed)
        float* UpdZ = (s & 1) ? Upd0 : Upd1;   // k2 zeros for next step
        k1_gemmH<<<dim3(64, 8), 256, 0, stream>>>(Mcur, Wcsw2, bc, W3sw2, UpdC);
        k2_update<<<256, 256, 0, stream>>>(b3, Scur, Snxt, Mnxt, UpdC, UpdZ);
        float* t = Scur; Scur = Snxt; Snxt = t;
        f16*   m = Mcur; Mcur = Mnxt; Mnxt = m;
    }

    // output = masked alpha plane = first 8192 floats of final state
    hipMemcpyAsync(d_out, Scur, NPIX * sizeof(float),
                   hipMemcpyDeviceToDevice, stream);
}

// Round 13
// 1398.300 us; speedup vs baseline: 1.3971x; 1.3971x over previous
//
#include <hip/hip_runtime.h>

// CAGenerator: 64-step neural CA — 2 dispatches/step, fence-free.
// R13 = R11 (best, 1480us) + latency tunings:
//   k1: Wc A-frag prefetch ring depth 4 -> 8 (L2-latency cover).
//   k2: W3 A-frags + H B-frags hoisted into registers before the MFMA chain.
// R12's 5M/step atomicAdd Upd fold REVERTED (L2 atomic serialization).
// Structure: k1 computes H = relu(Wc*im2col(S)) and accumulates the alpha
// dot into Aseed (65K coalesced atomics/step); k2 does upd = W3*H for its
// own row, live mask from Aseed/Sold, state write (Sf32 + Smf16), and seeds
// the next step's Aseed.
// Folded: Wc = W2@W1 (512x720), bc = W2@b1+b2. mask=uniform()<1.0 -> no RNG.
// K-permutation kp = tap*80+ci: B-fragment = one ds_read_b128 from msT.

#define NPIX 8192
#define T_ALIVE 0.01f

typedef _Float16 f16;
typedef __attribute__((ext_vector_type(8)))  _Float16 h8_t;
typedef __attribute__((ext_vector_type(4)))  _Float16 h4_t;
typedef __attribute__((ext_vector_type(16))) float    fx16;

// ---------------------------------------------------------------------------
// Prep
// ---------------------------------------------------------------------------
__global__ __launch_bounds__(256) void tr512(
    const float* __restrict__ W2, float* __restrict__ W2T)
{
    __shared__ float t[32][33];
    const int bx = blockIdx.x & 15, by = blockIdx.x >> 4;
    const int x = threadIdx.x & 31, y8 = threadIdx.x >> 5;
#pragma unroll
    for (int r = 0; r < 32; r += 8)
        t[r + y8][x] = W2[(size_t)(by * 32 + r + y8) * 512 + bx * 32 + x];
    __syncthreads();
#pragma unroll
    for (int r = 0; r < 32; r += 8)
        W2T[(size_t)(bx * 32 + r + y8) * 512 + by * 32 + x] = t[x][r + y8];
}

__global__ __launch_bounds__(256) void wc32(
    const float* __restrict__ W2T, const float* __restrict__ W1,
    float* __restrict__ Wc)
{
    __shared__ float As[16][32];
    __shared__ float Bs[16][32];
    const int tid = threadIdx.x;
    const int ty = tid >> 3, tx = tid & 7;
    const int m0 = blockIdx.y * 32, n0 = blockIdx.x * 32;
    float acc[4] = {0.f, 0.f, 0.f, 0.f};

    for (int k0 = 0; k0 < 512; k0 += 16) {
#pragma unroll
        for (int t = 0; t < 2; ++t) {
            const int idx = tid + t * 256;
            const int r = idx >> 5, c = idx & 31;
            As[r][c] = W2T[(size_t)(k0 + r) * 512 + m0 + c];
            const int n = n0 + c;
            Bs[r][c] = (n < 720) ? W1[(size_t)(k0 + r) * 720 + n] : 0.f;
        }
        __syncthreads();
#pragma unroll
        for (int kk = 0; kk < 16; ++kk) {
            const float a = As[kk][ty];
#pragma unroll
            for (int j = 0; j < 4; ++j)
                acc[j] = fmaf(a, Bs[kk][tx * 4 + j], acc[j]);
        }
        __syncthreads();
    }
    const int m = m0 + ty;
#pragma unroll
    for (int j = 0; j < 4; ++j) {
        const int n = n0 + tx * 4 + j;
        if (n < 720) Wc[(size_t)m * 720 + n] = acc[j];
    }
}

__global__ __launch_bounds__(256) void bc_k(
    const float* __restrict__ W2, const float* __restrict__ b1,
    const float* __restrict__ b2, float* __restrict__ bc)
{
    const int m = blockIdx.x * 256 + threadIdx.x;
    if (m >= 512) return;
    float a = b2[m];
    for (int h = 0; h < 512; ++h) a += W2[m * 512 + h] * b1[h];
    bc[m] = a;
}

// 32x32x16 A-frags, K permuted (kp = tap*80+ci), 720 = 45*16 exactly.
__global__ __launch_bounds__(256) void swz_wc2(
    const float* __restrict__ Wc, f16* __restrict__ Wcsw2)
{
    const int idx = blockIdx.x * 256 + threadIdx.x;
    if (idx >= 45 * 16 * 64) return;
    const int lane = idx & 63;
    const int t = idx >> 6;
    const int mtg = t & 15, ks = t >> 4;
    const int m = mtg * 32 + (lane & 31);
    const int k0 = ks * 16 + (lane >> 5) * 8;
    h8_t v;
#pragma unroll
    for (int j = 0; j < 8; ++j) {
        const int kp = k0 + j;
        const int tap = kp / 80, ci = kp - tap * 80;
        v[j] = (f16)Wc[(size_t)m * 720 + ci * 9 + tap];
    }
    *(h8_t*)(Wcsw2 + (size_t)idx * 8) = v;
}

// 32x32x16 A-frags for W3 (80x512 padded to 96 rows).
__global__ __launch_bounds__(256) void swz_w32(
    const float* __restrict__ W3, f16* __restrict__ W3sw2)
{
    const int idx = blockIdx.x * 256 + threadIdx.x;
    if (idx >= 32 * 3 * 64) return;
    const int lane = idx & 63;
    const int t = idx >> 6;
    const int mt = t % 3, ks2 = t / 3;
    const int m = mt * 32 + (lane & 31);
    const int k0 = ks2 * 16 + (lane >> 5) * 8;
    h8_t v;
#pragma unroll
    for (int j = 0; j < 8; ++j)
        v[j] = (f16)((m < 80) ? W3[(size_t)m * 512 + k0 + j] : 0.f);
    *(h8_t*)(W3sw2 + (size_t)idx * 8) = v;
}

__global__ __launch_bounds__(256) void seed_k(
    const float* __restrict__ z, float* __restrict__ Sf32,
    f16* __restrict__ Smf16)
{
    const int idx = blockIdx.x * 256 + threadIdx.x;
    if (idx >= 640) return;
    const int b = idx / 80, c = idx - b * 80;
    const int n = b * 1024 + 16 * 32 + 16;
    const float v = (c == 0) ? 1.f : z[b * 100 + (c - 1)];
    Sf32[(size_t)c * NPIX + n] = v;
    Smf16[(size_t)n * 80 + c] = (f16)v;
}

// Aseed init for step 0: Aseed = S0_ch0 + b3[0] (S0_ch0 = 1 at center px).
__global__ __launch_bounds__(256) void aseed_init(
    const float* __restrict__ b3, float* __restrict__ Aseed)
{
    const int idx = blockIdx.x * 256 + threadIdx.x;
    if (idx >= NPIX) return;
    Aseed[idx] = b3[0] + (((idx & 1023) == 528) ? 1.f : 0.f);
}

// ---------------------------------------------------------------------------
// K1: H = relu(Wc * im2col(S)) + alpha-dot accumulation.
// grid (64, 8): x = 4-row band (img b = pb>>3, rows y0..y0+3), y = mb
// (64-channel chunk). Wave w = row y0+w (32 px), 2 mt tiles per wave.
// A-frag prefetch ring depth 8 (R13: covers L2 latency).
// ---------------------------------------------------------------------------
__global__ __launch_bounds__(256) void k1_gemmH(
    const f16* __restrict__ Smf16, const f16* __restrict__ Wcsw2,
    const float* __restrict__ bc, const float* __restrict__ W3,
    f16* __restrict__ H, float* __restrict__ Aseed)
{
    __shared__ f16  msT[16320];     // 10 octets x (6 rows x 34 px) x 8 halfs
    __shared__ float bcL[64];
    __shared__ float waL[64];

    const int tid = threadIdx.x;
    const int lane = tid & 63, w = tid >> 6;
    const int li = lane & 31, q2 = lane >> 5;
    const int pb = blockIdx.x, mb = blockIdx.y;
    const int b = pb >> 3, y0 = (pb & 7) * 4;
    const int gb = b * 1024;

    if (tid < 64) {
        bcL[tid] = bc[mb * 64 + tid];
        waL[tid] = W3[mb * 64 + tid];      // W3 row 0
    }
    // stage masked state from pixel-major fp16 (contiguous 16B per (px,cc))
    for (int idx = tid; idx < 2040; idx += 256) {
        const int p = idx / 10, cc = idx - p * 10;
        const int r = p / 34, xi = p - r * 34;
        const int gx = xi - 1, y = y0 - 1 + r;
        h8_t v;
        if (((unsigned)y < 32u) & ((unsigned)gx < 32u)) {
            v = *(const h8_t*)(Smf16 + (size_t)(gb + y * 32 + gx) * 80 + cc * 8);
        } else {
#pragma unroll
            for (int j = 0; j < 8; ++j) v[j] = (f16)0.f;
        }
        *(h8_t*)(msT + (size_t)(cc * 204 + p) * 8) = v;
    }
    __syncthreads();

    int pxh[9];
#pragma unroll
    for (int t = 0; t < 9; ++t)
        pxh[t] = ((t / 3) * 34 + li + (t % 3)) * 8;
    const int wbase = w * 272;      // w * 34 * 8

    fx16 acc[2];
#pragma unroll
    for (int i = 0; i < 2; ++i)
#pragma unroll
        for (int r = 0; r < 16; ++r) acc[i][r] = 0.f;

    h8_t abuf[8][2];                // depth-8 prefetch ring (R13)
#pragma unroll
    for (int pk = 0; pk < 8; ++pk)
#pragma unroll
        for (int i = 0; i < 2; ++i)
            abuf[pk][i] = *(const h8_t*)(Wcsw2 +
                (((size_t)pk * 16 + (mb * 2 + i)) * 64 + lane) * 8);

#pragma unroll
    for (int ks = 0; ks < 45; ++ks) {
        const int o0 = 2 * ks, o1 = 2 * ks + 1;
        const int a0 = (o0 % 10) * 1632 + wbase + pxh[o0 / 10];
        const int a1 = (o1 % 10) * 1632 + wbase + pxh[o1 / 10];
        const h8_t bf = *(const h8_t*)(msT + (q2 ? a1 : a0));
        h8_t av[2];
#pragma unroll
        for (int i = 0; i < 2; ++i) av[i] = abuf[ks & 7][i];
        if (ks + 8 < 45) {
#pragma unroll
            for (int i = 0; i < 2; ++i)
                abuf[ks & 7][i] = *(const h8_t*)(Wcsw2 +
                    (((size_t)(ks + 8) * 16 + (mb * 2 + i)) * 64 + lane) * 8);
        }
#pragma unroll
        for (int i = 0; i < 2; ++i)
            acc[i] = __builtin_amdgcn_mfma_f32_32x32x16_f16(
                av[i], bf, acc[i], 0, 0, 0);
    }

    // epilogue: relu(acc + bc) -> H octet layout; alpha partial dot
    const size_t px = (size_t)(gb + (y0 + w) * 32 + li);
    float pd = 0.f;
#pragma unroll
    for (int i = 0; i < 2; ++i) {
#pragma unroll
        for (int aa = 0; aa < 4; ++aa) {
            const int chl = i * 32 + 8 * aa + 4 * q2;
            const int co = mb * 8 + i * 4 + aa;
            h4_t v4;
#pragma unroll
            for (int rb = 0; rb < 4; ++rb) {
                const float hv = fmaxf(acc[i][aa * 4 + rb] + bcL[chl + rb], 0.f);
                v4[rb] = (f16)hv;
                pd = fmaf(hv, waL[chl + rb], pd);
            }
            *(h4_t*)(H + ((size_t)co * NPIX + px) * 8 + 4 * q2) = v4;
        }
    }
    // combine lane (q2=0) with lane+32 (q2=1) partials, one atomic per px
    const float pd2 = __shfl_down(pd, 32);
    if (lane < 32) atomicAdd(&Aseed[px], pd + pd2);
}

// ---------------------------------------------------------------------------
// K2: upd = W3*H (own row only); live mask from Aseed (alphaN) + Sold ch0
// (alphaO); writes Snew / Smf16 / AseedNext. grid 256: b = blk>>5, y = blk&31.
// R13: W3 A-frags and H B-frags hoisted into registers before the MFMA chain.
// ---------------------------------------------------------------------------
__global__ __launch_bounds__(256) void k2_update(
    const f16* __restrict__ H, const f16* __restrict__ W3sw2,
    const float* __restrict__ b3,
    const float* __restrict__ Sold, float* __restrict__ Snew,
    f16* __restrict__ Smf16,
    const float* __restrict__ AseedC, float* __restrict__ AseedN)
{
    __shared__ float redT[12288];    // ((w*3+mt)*4+aa)*256 + lane*4, 48 KB
    __shared__ float alphaO3[96];
    __shared__ float alphaN3[96];
    __shared__ float b3L[80];
    __shared__ float livef[32];

    const int tid = threadIdx.x;
    const int lane = tid & 63, w = tid >> 6;
    const int li = lane & 31, q2 = lane >> 5;
    const int blk = blockIdx.x;
    const int b = blk >> 5, y = blk & 31;
    const int gb = b * 1024;
    const size_t px = (size_t)(gb + y * 32 + li);

    // hoisted fragment loads: 8 H B-frags + 24 W3 A-frags, all issued early
    h8_t hb[8], w3r[8][3];
#pragma unroll
    for (int k2 = 0; k2 < 8; ++k2) {
        const int ks2 = w * 8 + k2;
        hb[k2] = *(const h8_t*)(H + ((size_t)(ks2 * 2 + q2) * NPIX + px) * 8);
#pragma unroll
        for (int mt = 0; mt < 3; ++mt)
            w3r[k2][mt] = *(const h8_t*)(W3sw2 +
                (((size_t)ks2 * 3 + mt) * 64 + lane) * 8);
    }

    if (tid < 80) b3L[tid] = b3[tid];
    if (tid < 96) {
        const int r = tid >> 5, x = tid & 31, yy = y - 1 + r;
        const bool inb = (unsigned)yy < 32u;
        alphaO3[tid] = inb ? Sold[gb + yy * 32 + x]   : -1e30f;
        alphaN3[tid] = inb ? AseedC[gb + yy * 32 + x] : -1e30f;
    }

    fx16 acc3[3];
#pragma unroll
    for (int mt = 0; mt < 3; ++mt)
#pragma unroll
        for (int r = 0; r < 16; ++r) acc3[mt][r] = 0.f;
#pragma unroll
    for (int k2 = 0; k2 < 8; ++k2) {
#pragma unroll
        for (int mt = 0; mt < 3; ++mt)
            acc3[mt] = __builtin_amdgcn_mfma_f32_32x32x16_f16(
                w3r[k2][mt], hb[k2], acc3[mt], 0, 0, 0);
    }

    // stash partials
#pragma unroll
    for (int mt = 0; mt < 3; ++mt)
#pragma unroll
        for (int aa = 0; aa < 4; ++aa) {
            float4 v;
            v.x = acc3[mt][aa * 4 + 0]; v.y = acc3[mt][aa * 4 + 1];
            v.z = acc3[mt][aa * 4 + 2]; v.w = acc3[mt][aa * 4 + 3];
            *(float4*)(redT + (((w * 3 + mt) * 4 + aa) * 256 + lane * 4)) = v;
        }
    __syncthreads();

    // live mask for own row (3x3 window over alphaN/alphaO)
    if (tid < 32) {
        float mN = -1e30f, mO = -1e30f;
#pragma unroll
        for (int r = 0; r < 3; ++r)
#pragma unroll
            for (int dx = -1; dx <= 1; ++dx) {
                const int xx = tid + dx;
                if ((unsigned)xx < 32u) {
                    mN = fmaxf(mN, alphaN3[r * 32 + xx]);
                    mO = fmaxf(mO, alphaO3[r * 32 + xx]);
                }
            }
        livef[tid] = (mN > T_ALIVE && mO > T_ALIVE) ? 1.f : 0.f;
    }
    __syncthreads();

    // epilogue: waves 0..2 reduce + write Snew / Smf16 / AseedN
    if (w < 3) {
        const int mt = w;
        const float lv = livef[li];
#pragma unroll
        for (int aa = 0; aa < 4; ++aa) {
            const float4 s0 = *(float4*)(redT + (((0 * 3 + mt) * 4 + aa) * 256 + lane * 4));
            const float4 s1 = *(float4*)(redT + (((1 * 3 + mt) * 4 + aa) * 256 + lane * 4));
            const float4 s2 = *(float4*)(redT + (((2 * 3 + mt) * 4 + aa) * 256 + lane * 4));
            const float4 s3 = *(float4*)(redT + (((3 * 3 + mt) * 4 + aa) * 256 + lane * 4));
            const float t4[4] = {s0.x + s1.x + s2.x + s3.x,
                                 s0.y + s1.y + s2.y + s3.y,
                                 s0.z + s1.z + s2.z + s3.z,
                                 s0.w + s1.w + s2.w + s3.w};
            const int ch0 = mt * 32 + 8 * aa + 4 * q2;
            if (ch0 + 3 < 80) {
                h4_t v4;
                float vrb0 = 0.f;
#pragma unroll
                for (int rb = 0; rb < 4; ++rb) {
                    const int ch = ch0 + rb;
                    const size_t idx = (size_t)ch * NPIX + px;
                    const float v = (Sold[idx] + t4[rb] + b3L[ch]) * lv;
                    Snew[idx] = v;
                    v4[rb] = (f16)v;
                    if (rb == 0) vrb0 = v;
                }
                *(h4_t*)(Smf16 + px * 80 + ch0) = v4;
                // seed next step's alpha accumulator with Snew_ch0 + b3[0]
                if (mt == 0 && aa == 0 && q2 == 0)
                    AseedN[px] = vrb0 + b3L[0];
            }
        }
    }
}

// ---------------------------------------------------------------------------
extern "C" void kernel_launch(void* const* d_in, const int* in_sizes, int n_in,
                              void* d_out, int out_size, void* d_ws, size_t ws_size,
                              hipStream_t stream)
{
    const float* z  = (const float*)d_in[0];
    const float* W1 = (const float*)d_in[1];   // 512 x 720
    const float* b1 = (const float*)d_in[2];
    const float* W2 = (const float*)d_in[3];   // 512 x 512
    const float* b2 = (const float*)d_in[4];
    const float* W3 = (const float*)d_in[5];   // 80 x 512
    const float* b3 = (const float*)d_in[6];

    char* ws = (char*)d_ws;
    float* S0    = (float*)ws;  ws += (size_t)80 * NPIX * 4;
    float* S1    = (float*)ws;  ws += (size_t)80 * NPIX * 4;
    f16*   Sm0   = (f16*)ws;   ws += (size_t)NPIX * 80 * 2;
    f16*   Sm1   = (f16*)ws;   ws += (size_t)NPIX * 80 * 2;
    float* As0   = (float*)ws;  ws += NPIX * 4;
    float* As1   = (float*)ws;  ws += NPIX * 4;
    float* bc    = (float*)ws;  ws += 512 * 4;
    float* Wc    = (float*)ws;  ws += (size_t)512 * 720 * 4;
    float* W2T   = (float*)ws;  ws += (size_t)512 * 512 * 4;
    f16*   Wcsw2 = (f16*)ws;   ws += (size_t)45 * 16 * 64 * 8 * 2;
    f16*   W3sw2 = (f16*)ws;   ws += (size_t)32 * 3 * 64 * 8 * 2;
    f16*   H     = (f16*)ws;   ws += (size_t)64 * NPIX * 8 * 2;    // 8 MB

    hipMemsetAsync(S0, 0, (size_t)80 * NPIX * 4, stream);
    hipMemsetAsync(Sm0, 0, (size_t)NPIX * 80 * 2, stream);
    seed_k<<<3, 256, 0, stream>>>(z, S0, Sm0);
    aseed_init<<<32, 256, 0, stream>>>(b3, As0);
    tr512<<<256, 256, 0, stream>>>(W2, W2T);
    wc32<<<dim3(23, 16), 256, 0, stream>>>(W2T, W1, Wc);
    bc_k<<<2, 256, 0, stream>>>(W2, b1, b2, bc);
    swz_wc2<<<180, 256, 0, stream>>>(Wc, Wcsw2);
    swz_w32<<<24, 256, 0, stream>>>(W3, W3sw2);

    float* Scur = S0;  float* Snxt = S1;
    f16*   Mcur = Sm0; f16*   Mnxt = Sm1;
    for (int s = 0; s < 64; ++s) {
        float* AsC = (s & 1) ? As1 : As0;
        float* AsN = (s & 1) ? As0 : As1;
        k1_gemmH<<<dim3(64, 8), 256, 0, stream>>>(Mcur, Wcsw2, bc, W3, H, AsC);
        k2_update<<<256, 256, 0, stream>>>(H, W3sw2, b3, Scur, Snxt, Mnxt,
                                           AsC, AsN);
        float* t = Scur; Scur = Snxt; Snxt = t;
        f16*   m = Mcur; Mcur = Mnxt; Mnxt = m;
    }

    // output = masked alpha plane = first 8192 floats of final state
    hipMemcpyAsync(d_out, Scur, NPIX * sizeof(float),
                   hipMemcpyDeviceToDevice, stream);
}